// Round 10
// baseline (95.898 us; speedup 1.0000x reference)
//
#include <hip/hip_runtime.h>
#include <hip/hip_bf16.h>

#define NEMB 16

typedef short s16x8 __attribute__((ext_vector_type(8)));
typedef float f32x16 __attribute__((ext_vector_type(16)));

__device__ __forceinline__ unsigned int pack_bf16x2_rnd(float lo, float hi) {
    unsigned int ul = __float_as_uint(lo);
    unsigned int uh = __float_as_uint(hi);
    return ((ul + 0x8000u) >> 16) | ((uh + 0x8000u) & 0xffff0000u);
}
// truncate-pack [bf16(lo), bf16(hi)] into one u32 with a single v_perm
__device__ __forceinline__ unsigned int pack_bf16x2_trunc(float lo, float hi) {
    return __builtin_amdgcn_perm(__float_as_uint(hi), __float_as_uint(lo),
                                 0x07060302u);
}

// ---------------------------------------------------------------------------
// Kernel P: emb f32 -> bf16 table (3.2 MB, L2-resident). 8 floats/thread.
// ---------------------------------------------------------------------------
__global__ __launch_bounds__(256) void emb_to_bf16_kernel(
        const float* __restrict__ emb, unsigned int* __restrict__ embT,
        int nWords) {  // nWords = nNodes*8 (one word = 2 bf16)
    int i = (blockIdx.x * 256 + threadIdx.x) * 4;
    if (i + 4 <= nWords) {
        float4 a = *reinterpret_cast<const float4*>(emb + 2 * i);
        float4 b = *reinterpret_cast<const float4*>(emb + 2 * i + 4);
        uint4 r;
        r.x = pack_bf16x2_rnd(a.x, a.y);
        r.y = pack_bf16x2_rnd(a.z, a.w);
        r.z = pack_bf16x2_rnd(b.x, b.y);
        r.w = pack_bf16x2_rnd(b.z, b.w);
        *reinterpret_cast<uint4*>(embT + i) = r;
    } else {
        for (; i < nWords; ++i)
            embT[i] = pack_bf16x2_rnd(emb[2 * i], emb[2 * i + 1]);
    }
}

// ---------------------------------------------------------------------------
// Shared device helpers for the fused MLP kernels.
// Layout facts (verified r5-r9):
//   32x32x16 MFMA, swapped operands. D col = lane&31 = edge; D row n(r) =
//   (r&3)+8*(r>>2)+4*(lane>>5).  permlane32_swap: vdst_hi <-> vsrc_lo;
//   B-frag exchange needs x_hi <-> y_lo  =>  vdst = x, vsrc = y.
// ---------------------------------------------------------------------------
#define WAVES 4
#define ITERS_FLAT 32
#define EPB_FLAT (WAVES * 32 * ITERS_FLAT)   // 4096
#define ITERS_G 8
#define EPB_G (WAVES * 32 * ITERS_G)         // 1024

struct MlpConsts {
    s16x8 A1[2][2];
    s16x8 A2[4];
    f32x16 b1v0, b1v1, b2v;
    float w3v[16];
    float b3v;
};

__device__ __forceinline__ void load_consts(
        MlpConsts& C, int el, int hi,
        const float* __restrict__ W1, const float* __restrict__ b1,
        const float* __restrict__ W2, const float* __restrict__ b2,
        const float* __restrict__ W3, const float* __restrict__ b3) {
#pragma unroll
    for (int jt = 0; jt < 2; ++jt)
#pragma unroll
        for (int kh = 0; kh < 2; ++kh) {
            s16x8 a;
#pragma unroll
            for (int i = 0; i < 8; ++i) {
                float v = W1[(kh * 16 + hi * 8 + i) * 64 + jt * 32 + el];
                a[i] = (short)((__float_as_uint(v) + 0x8000u) >> 16);
            }
            C.A1[jt][kh] = a;
        }
#pragma unroll
    for (int f = 0; f < 4; ++f) {
        s16x8 a;
#pragma unroll
        for (int i = 0; i < 8; ++i) {
            float v = W2[(f * 16 + hi * 8 + i) * 32 + el];
            a[i] = (short)((__float_as_uint(v) + 0x8000u) >> 16);
        }
        C.A2[f] = a;
    }
#pragma unroll
    for (int r = 0; r < 16; ++r) {
        int n = (r & 3) + 8 * (r >> 2) + 4 * hi;
        C.b1v0[r] = b1[n];
        C.b1v1[r] = b1[32 + n];
        C.b2v[r]  = b2[n];
        C.w3v[r]  = W3[n];
    }
    C.b3v = b3[0];
}

// compute one 32-edge tile from gathered buffers; returns sigmoid prob
__device__ __forceinline__ float tile_mlp(const MlpConsts& C,
                                          uint4 esq, uint4 edq) {
    union { uint4 q; s16x8 v; } es, edr;
    es.q = esq; edr.q = edq;

    f32x16 a0 = __builtin_amdgcn_mfma_f32_32x32x16_bf16(C.A1[0][0], es.v,  C.b1v0, 0, 0, 0);
    a0        = __builtin_amdgcn_mfma_f32_32x32x16_bf16(C.A1[0][1], edr.v, a0,     0, 0, 0);
    f32x16 a1 = __builtin_amdgcn_mfma_f32_32x32x16_bf16(C.A1[1][0], es.v,  C.b1v1, 0, 0, 0);
    a1        = __builtin_amdgcn_mfma_f32_32x32x16_bf16(C.A1[1][1], edr.v, a1,     0, 0, 0);

    union { unsigned int u[4]; s16x8 v; } bf0, bf1, bf2, bf3;
#define MAKE_FRAG(BF, AT, M)                                                   \
    {                                                                          \
        unsigned int x0 = pack_bf16x2_trunc(fmaxf((AT)[8*(M)+0], 0.f),         \
                                            fmaxf((AT)[8*(M)+1], 0.f));        \
        unsigned int x1 = pack_bf16x2_trunc(fmaxf((AT)[8*(M)+2], 0.f),         \
                                            fmaxf((AT)[8*(M)+3], 0.f));        \
        unsigned int y0 = pack_bf16x2_trunc(fmaxf((AT)[8*(M)+4], 0.f),         \
                                            fmaxf((AT)[8*(M)+5], 0.f));        \
        unsigned int y1 = pack_bf16x2_trunc(fmaxf((AT)[8*(M)+6], 0.f),         \
                                            fmaxf((AT)[8*(M)+7], 0.f));        \
        asm("v_permlane32_swap_b32 %0, %1" : "+v"(x0), "+v"(y0));              \
        asm("v_permlane32_swap_b32 %0, %1" : "+v"(x1), "+v"(y1));              \
        BF.u[0] = x0; BF.u[1] = x1; BF.u[2] = y0; BF.u[3] = y1;                \
    }
    MAKE_FRAG(bf0, a0, 0)
    MAKE_FRAG(bf1, a0, 1)
    MAKE_FRAG(bf2, a1, 0)
    MAKE_FRAG(bf3, a1, 1)
#undef MAKE_FRAG

    f32x16 acc;
    acc = __builtin_amdgcn_mfma_f32_32x32x16_bf16(C.A2[0], bf0.v, C.b2v, 0, 0, 0);
    acc = __builtin_amdgcn_mfma_f32_32x32x16_bf16(C.A2[1], bf1.v, acc,   0, 0, 0);
    acc = __builtin_amdgcn_mfma_f32_32x32x16_bf16(C.A2[2], bf2.v, acc,   0, 0, 0);
    acc = __builtin_amdgcn_mfma_f32_32x32x16_bf16(C.A2[3], bf3.v, acc,   0, 0, 0);

    float pr[16];
#pragma unroll
    for (int r = 0; r < 16; ++r)
        pr[r] = fmaxf(acc[r], 0.0f) * C.w3v[r];
    float s8[8];
#pragma unroll
    for (int r = 0; r < 8; ++r) s8[r] = pr[2 * r] + pr[2 * r + 1];
    float s4[4];
#pragma unroll
    for (int r = 0; r < 4; ++r) s4[r] = s8[2 * r] + s8[2 * r + 1];
    float v = (s4[0] + s4[1]) + (s4[2] + s4[3]);
    {
        float va = v, vb = v;
        asm("v_permlane32_swap_b32 %0, %1" : "+v"(vb), "+v"(va));
        v = va + vb;
    }
    return 1.0f / (1.0f + __expf(-(v + C.b3v)));
}

// ---------------------------------------------------------------------------
// Flat kernel: NO bounds checks. Host guarantees it covers exactly
// gridDim.x * EPB_FLAT edges (<= nE). Rolling 1-ahead pipeline on both the
// ei loads and the table gathers.
// ---------------------------------------------------------------------------
__global__ __launch_bounds__(256) void edge_flat_kernel(
        const unsigned short* __restrict__ embT,
        const int* __restrict__ ei,
        const float* __restrict__ W1, const float* __restrict__ b1,
        const float* __restrict__ W2, const float* __restrict__ b2,
        const float* __restrict__ W3, const float* __restrict__ b3,
        float* __restrict__ out, int nE) {
    const int tid = threadIdx.x;
    const int w  = tid >> 6;
    const int l  = tid & 63;
    const int el = l & 31;
    const int hi = l >> 5;

    MlpConsts C;
    load_consts(C, el, hi, W1, b1, W2, b2, W3, b3);

    const int e0 = blockIdx.x * EPB_FLAT + w * 32 + el;  // this lane's edge @ it=0

    auto GATHER = [&](int s, int d, uint4& es, uint4& ed) {
        es = *reinterpret_cast<const uint4*>(embT + ((size_t)s << 4) + (hi << 3));
        ed = *reinterpret_cast<const uint4*>(embT + ((size_t)d << 4) + (hi << 3));
    };
    auto STORE = [&](float p, int e, int s, int d) {
        if (hi == 0) {
            out[e] = p;
            out[nE + e] = (float)s;
        } else {
            out[(size_t)2 * nE + e] = (float)d;
        }
    };

    // ---- prologue ----
    int sA = ei[e0];
    int dA = ei[nE + e0];
    uint4 esA, edA, esB, edB;
    GATHER(sA, dA, esA, edA);
    int sB = ei[e0 + 128];
    int dB = ei[nE + e0 + 128];

#pragma unroll 1
    for (int it = 0; it < ITERS_FLAT; it += 2) {
        GATHER(sB, dB, esB, edB);                      // tile it+1
        int sN = 0, dN = 0;
        if (it + 2 < ITERS_FLAT) {                     // indices for it+2
            sN = ei[e0 + (it + 2) * 128];
            dN = ei[nE + e0 + (it + 2) * 128];
        }
        {
            float p = tile_mlp(C, esA, edA);
            STORE(p, e0 + it * 128, sA, dA);
        }
        if (it + 2 < ITERS_FLAT) GATHER(sN, dN, esA, edA);  // tile it+2
        int sM = 0, dM = 0;
        if (it + 3 < ITERS_FLAT) {                     // indices for it+3
            sM = ei[e0 + (it + 3) * 128];
            dM = ei[nE + e0 + (it + 3) * 128];
        }
        {
            float p = tile_mlp(C, esB, edB);
            STORE(p, e0 + (it + 1) * 128, sB, dB);
        }
        sA = sN; dA = dN; sB = sM; dB = dM;
    }
}

// ---------------------------------------------------------------------------
// Guarded remainder kernel (edges [eStart, nE)), round-9 structure.
// ---------------------------------------------------------------------------
__global__ __launch_bounds__(256) void edge_guard_kernel(
        const unsigned short* __restrict__ embT,
        const int* __restrict__ ei,
        const float* __restrict__ W1, const float* __restrict__ b1,
        const float* __restrict__ W2, const float* __restrict__ b2,
        const float* __restrict__ W3, const float* __restrict__ b3,
        float* __restrict__ out, int nE, int eStart) {
    const int tid = threadIdx.x;
    const int w  = tid >> 6;
    const int l  = tid & 63;
    const int el = l & 31;
    const int hi = l >> 5;

    MlpConsts C;
    load_consts(C, el, hi, W1, b1, W2, b2, W3, b3);

    const int base0 = eStart + blockIdx.x * EPB_G + w * 32;

    int sv[ITERS_G], dv[ITERS_G];
#pragma unroll
    for (int i = 0; i < ITERS_G; ++i) {
        int e  = base0 + i * (WAVES * 32) + el;
        int ec = e < nE ? e : (nE - 1);
        sv[i] = ei[ec];
        dv[i] = ei[nE + ec];
    }

    auto GATHER = [&](int s, int d, uint4& es, uint4& ed) {
        es = *reinterpret_cast<const uint4*>(embT + ((size_t)s << 4) + (hi << 3));
        ed = *reinterpret_cast<const uint4*>(embT + ((size_t)d << 4) + (hi << 3));
    };
    auto DO_TILE = [&](uint4 es, uint4 ed, int it, int s, int d) {
        float p = tile_mlp(C, es, ed);
        int e = base0 + it * (WAVES * 32) + el;
        if (e < nE) {
            if (hi == 0) {
                out[e] = p;
                out[nE + e] = (float)s;
            } else {
                out[(size_t)2 * nE + e] = (float)d;
            }
        }
    };

    uint4 esA, edA, esB, edB;
    GATHER(sv[0], dv[0], esA, edA);
#pragma unroll
    for (int it = 0; it < ITERS_G; it += 2) {
        if (base0 + it * (WAVES * 32) >= nE) break;
        if (it + 1 < ITERS_G) GATHER(sv[it + 1], dv[it + 1], esB, edB);
        DO_TILE(esA, edA, it, sv[it], dv[it]);
        if (it + 2 < ITERS_G) GATHER(sv[it + 2], dv[it + 2], esA, edA);
        if (it + 1 < ITERS_G) DO_TILE(esB, edB, it + 1, sv[it + 1], dv[it + 1]);
    }
}

// ---------------------------------------------------------------------------
// Fallback: per-edge full MLP (no workspace), f32 output.
// ---------------------------------------------------------------------------
__global__ __launch_bounds__(256) void edge_mlp_naive_kernel(
        const float* __restrict__ emb, const int* __restrict__ ei,
        const float* __restrict__ W1, const float* __restrict__ b1,
        const float* __restrict__ W2, const float* __restrict__ b2,
        const float* __restrict__ W3, const float* __restrict__ b3,
        float* __restrict__ out, int nE) {
    __shared__ __align__(16) float sW1[32 * 64];
    __shared__ __align__(16) float sW2[64 * 32];
    __shared__ float sW3[32];
    __shared__ float sB1[64];
    __shared__ float sB2[32];
    __shared__ float sB3;
    for (int i = threadIdx.x; i < 2048; i += 256) {
        sW1[i] = W1[i];
        sW2[i] = W2[i];
    }
    if (threadIdx.x < 64) sB1[threadIdx.x] = b1[threadIdx.x];
    if (threadIdx.x < 32) {
        sW3[threadIdx.x] = W3[threadIdx.x];
        sB2[threadIdx.x] = b2[threadIdx.x];
    }
    if (threadIdx.x == 0) sB3 = b3[0];
    __syncthreads();

    int e = blockIdx.x * 256 + threadIdx.x;
    if (e >= nE) return;

    int s = ei[e];
    int d = ei[nE + e];

    float f[32];
    const float4* ps = reinterpret_cast<const float4*>(emb + (size_t)s * NEMB);
    const float4* pd = reinterpret_cast<const float4*>(emb + (size_t)d * NEMB);
#pragma unroll
    for (int q = 0; q < 4; ++q) {
        float4 v = ps[q];
        f[4 * q + 0] = v.x; f[4 * q + 1] = v.y; f[4 * q + 2] = v.z; f[4 * q + 3] = v.w;
    }
#pragma unroll
    for (int q = 0; q < 4; ++q) {
        float4 v = pd[q];
        f[16 + 4 * q + 0] = v.x; f[16 + 4 * q + 1] = v.y;
        f[16 + 4 * q + 2] = v.z; f[16 + 4 * q + 3] = v.w;
    }

    float h1[64];
#pragma unroll
    for (int j = 0; j < 64; j += 4) {
        float a0 = sB1[j + 0], a1 = sB1[j + 1], a2 = sB1[j + 2], a3 = sB1[j + 3];
#pragma unroll
        for (int k = 0; k < 32; ++k) {
            float4 wv = *reinterpret_cast<const float4*>(sW1 + k * 64 + j);
            a0 = fmaf(f[k], wv.x, a0);
            a1 = fmaf(f[k], wv.y, a1);
            a2 = fmaf(f[k], wv.z, a2);
            a3 = fmaf(f[k], wv.w, a3);
        }
        h1[j + 0] = fmaxf(a0, 0.0f);
        h1[j + 1] = fmaxf(a1, 0.0f);
        h1[j + 2] = fmaxf(a2, 0.0f);
        h1[j + 3] = fmaxf(a3, 0.0f);
    }

    float acc = sB3;
#pragma unroll
    for (int j = 0; j < 32; j += 4) {
        float a0 = sB2[j + 0], a1 = sB2[j + 1], a2 = sB2[j + 2], a3 = sB2[j + 3];
#pragma unroll
        for (int k = 0; k < 64; ++k) {
            float4 wv = *reinterpret_cast<const float4*>(sW2 + k * 32 + j);
            a0 = fmaf(h1[k], wv.x, a0);
            a1 = fmaf(h1[k], wv.y, a1);
            a2 = fmaf(h1[k], wv.z, a2);
            a3 = fmaf(h1[k], wv.w, a3);
        }
        acc = fmaf(fmaxf(a0, 0.0f), sW3[j + 0], acc);
        acc = fmaf(fmaxf(a1, 0.0f), sW3[j + 1], acc);
        acc = fmaf(fmaxf(a2, 0.0f), sW3[j + 2], acc);
        acc = fmaf(fmaxf(a3, 0.0f), sW3[j + 3], acc);
    }

    out[e] = 1.0f / (1.0f + __expf(-acc));
}

__global__ __launch_bounds__(256) void edge_idx_copy_kernel(
        const int* __restrict__ ei, float* __restrict__ out, int n) {
    int i = (blockIdx.x * 256 + threadIdx.x) * 4;
    if (i + 4 <= n) {
        int4 a = *reinterpret_cast<const int4*>(ei + i);
        float4 r = make_float4((float)a.x, (float)a.y, (float)a.z, (float)a.w);
        *reinterpret_cast<float4*>(out + i) = r;
    } else {
        for (; i < n; ++i) out[i] = (float)ei[i];
    }
}

extern "C" void kernel_launch(void* const* d_in, const int* in_sizes, int n_in,
                              void* d_out, int out_size, void* d_ws, size_t ws_size,
                              hipStream_t stream) {
    const float* emb = (const float*)d_in[0];
    const int*   ei  = (const int*)d_in[1];
    const float* W1  = (const float*)d_in[2];
    const float* b1  = (const float*)d_in[3];
    const float* W2  = (const float*)d_in[4];
    const float* b2  = (const float*)d_in[5];
    const float* W3  = (const float*)d_in[6];
    const float* b3  = (const float*)d_in[7];

    const int nNodes = in_sizes[0] / NEMB;   // 100000
    const int n2E    = in_sizes[1];          // 2 * E
    const int nE     = n2E / 2;              // E (= 2^22 in this problem)

    float* out = (float*)d_out;  // f32: [E probs][2E edge indices]

    const size_t tbl_bytes = (size_t)nNodes * NEMB * sizeof(unsigned short);  // 3.2 MB
    const bool use_ws = (ws_size >= tbl_bytes);

    if (use_ws) {
        unsigned int* embT = (unsigned int*)d_ws;
        const int nWords = nNodes * 8;
        emb_to_bf16_kernel<<<(nWords / 4 + 255) / 256, 256, 0, stream>>>(
            emb, embT, nWords);

        const int nFlatBlocks = nE / EPB_FLAT;       // 1024 at E = 2^22
        const int nFlat = nFlatBlocks * EPB_FLAT;
        if (nFlatBlocks > 0) {
            edge_flat_kernel<<<nFlatBlocks, 256, 0, stream>>>(
                (const unsigned short*)embT, ei, W1, b1, W2, b2, W3, b3, out, nE);
        }
        const int rem = nE - nFlat;                  // 0 at E = 2^22
        if (rem > 0) {
            const int gBlocks = (rem + EPB_G - 1) / EPB_G;
            edge_guard_kernel<<<gBlocks, 256, 0, stream>>>(
                (const unsigned short*)embT, ei, W1, b1, W2, b2, W3, b3, out, nE,
                nFlat);
        }
    } else {
        edge_mlp_naive_kernel<<<(nE + 255) / 256, 256, 0, stream>>>(
            emb, ei, W1, b1, W2, b2, W3, b3, out, nE);
        edge_idx_copy_kernel<<<((n2E + 3) / 4 + 255) / 256, 256, 0, stream>>>(
            ei, out + nE, n2E);
    }
}

// Round 11
// 87.752 us; speedup vs baseline: 1.0928x; 1.0928x over previous
//
#include <hip/hip_runtime.h>
#include <hip/hip_bf16.h>

#define NEMB 16

typedef short s16x8 __attribute__((ext_vector_type(8)));
typedef float f32x16 __attribute__((ext_vector_type(16)));

__device__ __forceinline__ unsigned int pack_bf16x2_rnd(float lo, float hi) {
    unsigned int ul = __float_as_uint(lo);
    unsigned int uh = __float_as_uint(hi);
    return ((ul + 0x8000u) >> 16) | ((uh + 0x8000u) & 0xffff0000u);
}
// truncate-pack [bf16(lo), bf16(hi)] into one u32 with a single v_perm
__device__ __forceinline__ unsigned int pack_bf16x2_trunc(float lo, float hi) {
    return __builtin_amdgcn_perm(__float_as_uint(hi), __float_as_uint(lo),
                                 0x07060302u);
}

// ---------------------------------------------------------------------------
// Kernel P: emb f32 -> bf16 table (3.2 MB, L2-resident). 8 floats/thread.
// ---------------------------------------------------------------------------
__global__ __launch_bounds__(256) void emb_to_bf16_kernel(
        const float* __restrict__ emb, unsigned int* __restrict__ embT,
        int nWords) {  // nWords = nNodes*8 (one word = 2 bf16)
    int i = (blockIdx.x * 256 + threadIdx.x) * 4;
    if (i + 4 <= nWords) {
        float4 a = *reinterpret_cast<const float4*>(emb + 2 * i);
        float4 b = *reinterpret_cast<const float4*>(emb + 2 * i + 4);
        uint4 r;
        r.x = pack_bf16x2_rnd(a.x, a.y);
        r.y = pack_bf16x2_rnd(a.z, a.w);
        r.z = pack_bf16x2_rnd(b.x, b.y);
        r.w = pack_bf16x2_rnd(b.z, b.w);
        *reinterpret_cast<uint4*>(embT + i) = r;
    } else {
        for (; i < nWords; ++i)
            embT[i] = pack_bf16x2_rnd(emb[2 * i], emb[2 * i + 1]);
    }
}

// ---------------------------------------------------------------------------
// Fused MLP kernel (r9 structure + 3-deep gather pipeline + setprio).
// Layout facts (verified r5-r9):
//   32x32x16 MFMA, swapped operands. D col = lane&31 = edge; D row n(r) =
//   (r&3)+8*(r>>2)+4*(lane>>5).  permlane32_swap: vdst_hi <-> vsrc_lo;
//   B-frag exchange needs x_hi <-> y_lo  =>  vdst = x, vsrc = y.
// ---------------------------------------------------------------------------
#define WAVES 4
#define ITERS 8
#define EDGES_PER_BLOCK (WAVES * 32 * ITERS)   // 1024

__global__ __launch_bounds__(256) void edge_fused4_kernel(
        const unsigned short* __restrict__ embT,
        const int* __restrict__ ei,
        const float* __restrict__ W1, const float* __restrict__ b1,
        const float* __restrict__ W2, const float* __restrict__ b2,
        const float* __restrict__ W3, const float* __restrict__ b3,
        float* __restrict__ out, int nE) {
    const int tid = threadIdx.x;
    const int w  = tid >> 6;       // wave 0..3
    const int l  = tid & 63;
    const int el = l & 31;         // edge slot / D col
    const int hi = l >> 5;         // k/n half select

    // ---- Layer-1 A-frags: A1[jt][kh][i] = W1[kh*16 + hi*8 + i][jt*32 + el] ----
    s16x8 A1[2][2];
#pragma unroll
    for (int jt = 0; jt < 2; ++jt)
#pragma unroll
        for (int kh = 0; kh < 2; ++kh) {
            s16x8 a;
#pragma unroll
            for (int i = 0; i < 8; ++i) {
                float v = W1[(kh * 16 + hi * 8 + i) * 64 + jt * 32 + el];
                a[i] = (short)((__float_as_uint(v) + 0x8000u) >> 16);
            }
            A1[jt][kh] = a;
        }
    // ---- Layer-2 A-frags: A2[f][i] = W2[f*16 + hi*8 + i][el] ----
    s16x8 A2[4];
#pragma unroll
    for (int f = 0; f < 4; ++f) {
        s16x8 a;
#pragma unroll
        for (int i = 0; i < 8; ++i) {
            float v = W2[(f * 16 + hi * 8 + i) * 32 + el];
            a[i] = (short)((__float_as_uint(v) + 0x8000u) >> 16);
        }
        A2[f] = a;
    }
    // ---- per-lane C-init / epilogue vectors: n(r) = (r&3)+8*(r>>2)+4*hi ----
    f32x16 b1v0, b1v1, b2v;
    float w3v[16];
#pragma unroll
    for (int r = 0; r < 16; ++r) {
        int n = (r & 3) + 8 * (r >> 2) + 4 * hi;
        b1v0[r] = b1[n];
        b1v1[r] = b1[32 + n];
        b2v[r]  = b2[n];
        w3v[r]  = W3[n];
    }
    const float b3v = b3[0];

    const int base0 = blockIdx.x * EDGES_PER_BLOCK + w * 32;

    // ---- prologue: all ei loads (coalesced, issued together) ----
    int sv[ITERS], dv[ITERS];
#pragma unroll
    for (int i = 0; i < ITERS; ++i) {
        int e  = base0 + i * (WAVES * 32) + el;
        int ec = e < nE ? e : (nE - 1);
        sv[i] = ei[ec];
        dv[i] = ei[nE + ec];
    }

    auto GATHER = [&](int s, int d, uint4& es, uint4& ed) {
        es = *reinterpret_cast<const uint4*>(embT + ((size_t)s << 4) + (hi << 3));
        ed = *reinterpret_cast<const uint4*>(embT + ((size_t)d << 4) + (hi << 3));
    };

    auto DO_TILE = [&](uint4 esq, uint4 edq, int it, int s, int d) {
        union { uint4 q; s16x8 v; } es, edr;
        es.q = esq; edr.q = edq;

        __builtin_amdgcn_s_setprio(1);
        // ---- layer 1: two j-tiles, K=32 over [emb_s; emb_d] ----
        f32x16 a0 = __builtin_amdgcn_mfma_f32_32x32x16_bf16(A1[0][0], es.v,  b1v0, 0, 0, 0);
        a0        = __builtin_amdgcn_mfma_f32_32x32x16_bf16(A1[0][1], edr.v, a0,   0, 0, 0);
        f32x16 a1 = __builtin_amdgcn_mfma_f32_32x32x16_bf16(A1[1][0], es.v,  b1v1, 0, 0, 0);
        a1        = __builtin_amdgcn_mfma_f32_32x32x16_bf16(A1[1][1], edr.v, a1,   0, 0, 0);

        // ---- relu + pack all four B-frags, then 4 MFMAs ----
        union { unsigned int u[4]; s16x8 v; } bf0, bf1, bf2, bf3;
#define MAKE_FRAG(BF, AT, M)                                                   \
        {                                                                      \
            unsigned int x0 = pack_bf16x2_trunc(fmaxf((AT)[8*(M)+0], 0.f),     \
                                                fmaxf((AT)[8*(M)+1], 0.f));    \
            unsigned int x1 = pack_bf16x2_trunc(fmaxf((AT)[8*(M)+2], 0.f),     \
                                                fmaxf((AT)[8*(M)+3], 0.f));    \
            unsigned int y0 = pack_bf16x2_trunc(fmaxf((AT)[8*(M)+4], 0.f),     \
                                                fmaxf((AT)[8*(M)+5], 0.f));    \
            unsigned int y1 = pack_bf16x2_trunc(fmaxf((AT)[8*(M)+6], 0.f),     \
                                                fmaxf((AT)[8*(M)+7], 0.f));    \
            asm("v_permlane32_swap_b32 %0, %1" : "+v"(x0), "+v"(y0));          \
            asm("v_permlane32_swap_b32 %0, %1" : "+v"(x1), "+v"(y1));          \
            BF.u[0] = x0; BF.u[1] = x1; BF.u[2] = y0; BF.u[3] = y1;            \
        }
        MAKE_FRAG(bf0, a0, 0)
        MAKE_FRAG(bf1, a0, 1)
        MAKE_FRAG(bf2, a1, 0)
        MAKE_FRAG(bf3, a1, 1)
#undef MAKE_FRAG

        f32x16 acc;
        acc = __builtin_amdgcn_mfma_f32_32x32x16_bf16(A2[0], bf0.v, b2v, 0, 0, 0);
        acc = __builtin_amdgcn_mfma_f32_32x32x16_bf16(A2[1], bf1.v, acc, 0, 0, 0);
        acc = __builtin_amdgcn_mfma_f32_32x32x16_bf16(A2[2], bf2.v, acc, 0, 0, 0);
        acc = __builtin_amdgcn_mfma_f32_32x32x16_bf16(A2[3], bf3.v, acc, 0, 0, 0);
        __builtin_amdgcn_s_setprio(0);

        // ---- layer 3: independent products + add tree ----
        float pr[16];
#pragma unroll
        for (int r = 0; r < 16; ++r)
            pr[r] = fmaxf(acc[r], 0.0f) * w3v[r];
        float s8[8];
#pragma unroll
        for (int r = 0; r < 8; ++r) s8[r] = pr[2 * r] + pr[2 * r + 1];
        float s4[4];
#pragma unroll
        for (int r = 0; r < 4; ++r) s4[r] = s8[2 * r] + s8[2 * r + 1];
        float v = (s4[0] + s4[1]) + (s4[2] + s4[3]);
        {
            float va = v, vb = v;
            asm("v_permlane32_swap_b32 %0, %1" : "+v"(vb), "+v"(va));
            v = va + vb;
        }

        float p = 1.0f / (1.0f + __expf(-(v + b3v)));

        int e = base0 + it * (WAVES * 32) + el;
        if (e < nE) {
            if (hi == 0) {
                out[e] = p;                          // probs
                out[nE + e] = (float)s;              // edge_index row 0
            } else {
                out[(size_t)2 * nE + e] = (float)d;  // edge_index row 1
            }
        }
    };

    // ---- 3-deep pipeline, fully static buffer rotation (it mod 3) ----
    uint4 esX, edX, esY, edY, esZ, edZ;
    GATHER(sv[0], dv[0], esX, edX);
    GATHER(sv[1], dv[1], esY, edY);

    GATHER(sv[2], dv[2], esZ, edZ);  DO_TILE(esX, edX, 0, sv[0], dv[0]);
    GATHER(sv[3], dv[3], esX, edX);  DO_TILE(esY, edY, 1, sv[1], dv[1]);
    GATHER(sv[4], dv[4], esY, edY);  DO_TILE(esZ, edZ, 2, sv[2], dv[2]);
    GATHER(sv[5], dv[5], esZ, edZ);  DO_TILE(esX, edX, 3, sv[3], dv[3]);
    GATHER(sv[6], dv[6], esX, edX);  DO_TILE(esY, edY, 4, sv[4], dv[4]);
    GATHER(sv[7], dv[7], esY, edY);  DO_TILE(esZ, edZ, 5, sv[5], dv[5]);
    DO_TILE(esX, edX, 6, sv[6], dv[6]);
    DO_TILE(esY, edY, 7, sv[7], dv[7]);
}

// ---------------------------------------------------------------------------
// Fallback: per-edge full MLP (no workspace), f32 output.
// ---------------------------------------------------------------------------
__global__ __launch_bounds__(256) void edge_mlp_naive_kernel(
        const float* __restrict__ emb, const int* __restrict__ ei,
        const float* __restrict__ W1, const float* __restrict__ b1,
        const float* __restrict__ W2, const float* __restrict__ b2,
        const float* __restrict__ W3, const float* __restrict__ b3,
        float* __restrict__ out, int nE) {
    __shared__ __align__(16) float sW1[32 * 64];
    __shared__ __align__(16) float sW2[64 * 32];
    __shared__ float sW3[32];
    __shared__ float sB1[64];
    __shared__ float sB2[32];
    __shared__ float sB3;
    for (int i = threadIdx.x; i < 2048; i += 256) {
        sW1[i] = W1[i];
        sW2[i] = W2[i];
    }
    if (threadIdx.x < 64) sB1[threadIdx.x] = b1[threadIdx.x];
    if (threadIdx.x < 32) {
        sW3[threadIdx.x] = W3[threadIdx.x];
        sB2[threadIdx.x] = b2[threadIdx.x];
    }
    if (threadIdx.x == 0) sB3 = b3[0];
    __syncthreads();

    int e = blockIdx.x * 256 + threadIdx.x;
    if (e >= nE) return;

    int s = ei[e];
    int d = ei[nE + e];

    float f[32];
    const float4* ps = reinterpret_cast<const float4*>(emb + (size_t)s * NEMB);
    const float4* pd = reinterpret_cast<const float4*>(emb + (size_t)d * NEMB);
#pragma unroll
    for (int q = 0; q < 4; ++q) {
        float4 v = ps[q];
        f[4 * q + 0] = v.x; f[4 * q + 1] = v.y; f[4 * q + 2] = v.z; f[4 * q + 3] = v.w;
    }
#pragma unroll
    for (int q = 0; q < 4; ++q) {
        float4 v = pd[q];
        f[16 + 4 * q + 0] = v.x; f[16 + 4 * q + 1] = v.y;
        f[16 + 4 * q + 2] = v.z; f[16 + 4 * q + 3] = v.w;
    }

    float h1[64];
#pragma unroll
    for (int j = 0; j < 64; j += 4) {
        float a0 = sB1[j + 0], a1 = sB1[j + 1], a2 = sB1[j + 2], a3 = sB1[j + 3];
#pragma unroll
        for (int k = 0; k < 32; ++k) {
            float4 wv = *reinterpret_cast<const float4*>(sW1 + k * 64 + j);
            a0 = fmaf(f[k], wv.x, a0);
            a1 = fmaf(f[k], wv.y, a1);
            a2 = fmaf(f[k], wv.z, a2);
            a3 = fmaf(f[k], wv.w, a3);
        }
        h1[j + 0] = fmaxf(a0, 0.0f);
        h1[j + 1] = fmaxf(a1, 0.0f);
        h1[j + 2] = fmaxf(a2, 0.0f);
        h1[j + 3] = fmaxf(a3, 0.0f);
    }

    float acc = sB3;
#pragma unroll
    for (int j = 0; j < 32; j += 4) {
        float a0 = sB2[j + 0], a1 = sB2[j + 1], a2 = sB2[j + 2], a3 = sB2[j + 3];
#pragma unroll
        for (int k = 0; k < 64; ++k) {
            float4 wv = *reinterpret_cast<const float4*>(sW2 + k * 32 + j);
            a0 = fmaf(h1[k], wv.x, a0);
            a1 = fmaf(h1[k], wv.y, a1);
            a2 = fmaf(h1[k], wv.z, a2);
            a3 = fmaf(h1[k], wv.w, a3);
        }
        acc = fmaf(fmaxf(a0, 0.0f), sW3[j + 0], acc);
        acc = fmaf(fmaxf(a1, 0.0f), sW3[j + 1], acc);
        acc = fmaf(fmaxf(a2, 0.0f), sW3[j + 2], acc);
        acc = fmaf(fmaxf(a3, 0.0f), sW3[j + 3], acc);
    }

    out[e] = 1.0f / (1.0f + __expf(-acc));
}

__global__ __launch_bounds__(256) void edge_idx_copy_kernel(
        const int* __restrict__ ei, float* __restrict__ out, int n) {
    int i = (blockIdx.x * 256 + threadIdx.x) * 4;
    if (i + 4 <= n) {
        int4 a = *reinterpret_cast<const int4*>(ei + i);
        float4 r = make_float4((float)a.x, (float)a.y, (float)a.z, (float)a.w);
        *reinterpret_cast<float4*>(out + i) = r;
    } else {
        for (; i < n; ++i) out[i] = (float)ei[i];
    }
}

extern "C" void kernel_launch(void* const* d_in, const int* in_sizes, int n_in,
                              void* d_out, int out_size, void* d_ws, size_t ws_size,
                              hipStream_t stream) {
    const float* emb = (const float*)d_in[0];
    const int*   ei  = (const int*)d_in[1];
    const float* W1  = (const float*)d_in[2];
    const float* b1  = (const float*)d_in[3];
    const float* W2  = (const float*)d_in[4];
    const float* b2  = (const float*)d_in[5];
    const float* W3  = (const float*)d_in[6];
    const float* b3  = (const float*)d_in[7];

    const int nNodes = in_sizes[0] / NEMB;   // 100000
    const int n2E    = in_sizes[1];          // 2 * E
    const int nE     = n2E / 2;              // E

    float* out = (float*)d_out;  // f32: [E probs][2E edge indices]

    const size_t tbl_bytes = (size_t)nNodes * NEMB * sizeof(unsigned short);  // 3.2 MB
    const bool use_ws = (ws_size >= tbl_bytes);

    if (use_ws) {
        unsigned int* embT = (unsigned int*)d_ws;
        const int nWords = nNodes * 8;
        emb_to_bf16_kernel<<<(nWords / 4 + 255) / 256, 256, 0, stream>>>(
            emb, embT, nWords);

        edge_fused4_kernel<<<(nE + EDGES_PER_BLOCK - 1) / EDGES_PER_BLOCK, 256, 0,
                             stream>>>(
            (const unsigned short*)embT, ei, W1, b1, W2, b2, W3, b3, out, nE);
        // edge-index copy fused into edge_fused4_kernel
    } else {
        edge_mlp_naive_kernel<<<(nE + 255) / 256, 256, 0, stream>>>(
            emb, ei, W1, b1, W2, b2, W3, b3, out, nE);
        edge_idx_copy_kernel<<<((n2E + 3) / 4 + 255) / 256, 256, 0, stream>>>(
            ei, out + nE, n2E);
    }
}